// Round 14
// baseline (176.415 us; speedup 1.0000x reference)
//
#include <hip/hip_runtime.h>

#define B 16
#define F_DIM 256
#define P 8192
#define C 96
#define H 256
#define NSEG (B * C)          // 1536
#define G 8                   // feature rows per pool block
#define NFBLK (F_DIM / G)     // 32
#define SPLIT 4               // P split factor
#define PQ (P / SPLIT)        // 2048 points per block
#define NGRP (NSEG / 8)       // 192 row-groups

// Signed-int max on raw float bits == float max whenever true max >= 0.
// All-negative buckets return a negative value; every cnt!=P bucket gets
// relu() in the epilogue, so the result is still exact. Seed INT_MIN = -0.0f.

// R9-exact pool (best measured) + zeroing of the fused-MLP sync flags.
__global__ __launch_bounds__(256) void pool_kernel(const float* __restrict__ feat,
                                                   const int* __restrict__ label,
                                                   int* __restrict__ kbuf,
                                                   int* __restrict__ cnts,
                                                   int* __restrict__ flags) {
    __shared__ int smax[G][C];
    __shared__ int hist[C];
    const int blk = blockIdx.x;
    const int q  = blk & 3;            // P-quarter
    const int fg = (blk >> 2) & 31;    // feature group
    const int b  = blk >> 7;           // batch
    const int f0 = fg << 3;
    const int t = threadIdx.x;

    if (blk == 0) {                    // zero done1/done2 for fused_mlp
        for (int i = t; i < 2 * NGRP; i += 256) flags[i] = 0;
    }

    for (int i = t; i < G * C; i += 256) ((int*)smax)[i] = 0x80000000;  // -0.0f
    if (t < C) hist[t] = 0;
    __syncthreads();

    const int4* lrow4 = (const int4*)(label + (size_t)b * P + (size_t)q * PQ);
    int4 lab[2];
    lab[0] = lrow4[t];
    lab[1] = lrow4[t + 256];

    if (fg == 0) {   // one fg per (b,q) computes the quarter-histogram
        #pragma unroll
        for (int j = 0; j < 2; ++j) {
            atomicAdd(&hist[lab[j].x], 1);
            atomicAdd(&hist[lab[j].y], 1);
            atomicAdd(&hist[lab[j].z], 1);
            atomicAdd(&hist[lab[j].w], 1);
        }
    }

    const float4* fbase4 = (const float4*)(feat + ((size_t)b * F_DIM + f0) * P + (size_t)q * PQ);

    float4 cur[2], nxt[2];
    cur[0] = fbase4[t];
    cur[1] = fbase4[t + 256];

    #pragma unroll
    for (int f = 0; f < G; ++f) {
        if (f + 1 < G) {
            nxt[0] = fbase4[(size_t)(f + 1) * (P / 4) + t];
            nxt[1] = fbase4[(size_t)(f + 1) * (P / 4) + t + 256];
        }
        #pragma unroll
        for (int j = 0; j < 2; ++j) {
            atomicMax(&smax[f][lab[j].x], __float_as_int(cur[j].x));
            atomicMax(&smax[f][lab[j].y], __float_as_int(cur[j].y));
            atomicMax(&smax[f][lab[j].z], __float_as_int(cur[j].z));
            atomicMax(&smax[f][lab[j].w], __float_as_int(cur[j].w));
        }
        cur[0] = nxt[0];
        cur[1] = nxt[1];
    }
    __syncthreads();

    if (fg == 0 && t < C) cnts[q * NSEG + b * C + t] = hist[t];

    if (t < C) {
        int4 lo, hi;
        lo.x = smax[0][t]; lo.y = smax[1][t]; lo.z = smax[2][t]; lo.w = smax[3][t];
        hi.x = smax[4][t]; hi.y = smax[5][t]; hi.z = smax[6][t]; hi.w = smax[7][t];
        int* dst = kbuf + (size_t)q * NSEG * F_DIM + (size_t)(b * C + t) * F_DIM + f0;
        *(int4*)dst = lo;
        *(int4*)(dst + 4) = hi;
    }
}

// bounded acquire-spin until *p == 4 (device scope; invalidates L1/L2 on exit)
__device__ __forceinline__ void spin4(int* p) {
    int it = 0;
    while (__hip_atomic_load(p, __ATOMIC_ACQUIRE, __HIP_MEMORY_SCOPE_AGENT) != 4) {
        __builtin_amdgcn_s_sleep(8);
        if (++it > (1 << 20)) break;   // bounded: never hang the harness
    }
}

// Fused 3-layer MLP. Grid 768 = 192 groups x 4 blocks. Group i owns rows
// 8i..8i+7; block j owns 64-col tiles (48-col for logits, j<2 only).
// Intra-group sync via release-add / acquire-spin on done1/done2 (AGENT scope
// for cross-XCD visibility of h1/h2).
__global__ __launch_bounds__(256, 3) void fused_mlp(const int* __restrict__ kx,
                                                    const int* __restrict__ cnts,
                                                    const float* __restrict__ w1,
                                                    const float* __restrict__ b1,
                                                    const float* __restrict__ w2,
                                                    const float* __restrict__ b2,
                                                    const float* __restrict__ wl,
                                                    const float* __restrict__ bl,
                                                    float* __restrict__ h1,
                                                    float* __restrict__ h2,
                                                    float* __restrict__ out,
                                                    int* __restrict__ done1,
                                                    int* __restrict__ done2) {
    __shared__ float xs[8][H];
    __shared__ float ps[8][64][17];
    const int t = threadIdx.x;
    const int grp = blockIdx.x >> 2;
    const int j = blockIdx.x & 3;
    const int row0 = grp * 8;
    const int s = t >> 4;     // k-slice 0..15
    const int jq = t & 15;    // col-quad 0..15

    // ---- phase 1: h1 tile = relu(pooled @ w1 + b1), cols 64j..64j+63 ----
    {
        const int4* k4 = (const int4*)kx;
        const size_t base = (size_t)row0 * (H / 4);
        #pragma unroll
        for (int jj = 0; jj < 2; ++jj) {
            const int i = t + jj * 256;
            int4 km = k4[base + i];
            #pragma unroll
            for (int h = 1; h < SPLIT; ++h) {
                const int4 kh = k4[(size_t)h * NSEG * (H / 4) + base + i];
                km.x = km.x > kh.x ? km.x : kh.x;
                km.y = km.y > kh.y ? km.y : kh.y;
                km.z = km.z > kh.z ? km.z : kh.z;
                km.w = km.w > kh.w ? km.w : kh.w;
            }
            const int row = row0 + (i >> 6);
            const int cnt = cnts[row] + cnts[NSEG + row] +
                            cnts[2 * NSEG + row] + cnts[3 * NSEG + row];
            float4 v;
            v.x = __int_as_float(km.x); v.y = __int_as_float(km.y);
            v.z = __int_as_float(km.z); v.w = __int_as_float(km.w);
            if (cnt == 0) {
                v.x = v.y = v.z = v.w = 0.0f;
            } else if (cnt != P) {
                v.x = fmaxf(v.x, 0.0f); v.y = fmaxf(v.y, 0.0f);
                v.z = fmaxf(v.z, 0.0f); v.w = fmaxf(v.w, 0.0f);
            }
            ((float4*)xs)[i] = v;
        }
    }
    __syncthreads();
    {
        const int bj0 = 64 * j;
        const float4* w4 = (const float4*)w1;
        const int wq = (bj0 >> 2) + jq;
        const int kbase = s * 16;
        float4 acc[8];
        #pragma unroll
        for (int r = 0; r < 8; ++r) acc[r] = (float4){0.f, 0.f, 0.f, 0.f};
        #pragma unroll
        for (int i = 0; i < 16; ++i) {
            const int k = kbase + i;
            const float4 wv = w4[k * (H / 4) + wq];
            #pragma unroll
            for (int r = 0; r < 8; ++r) {
                const float xv = xs[r][k];
                acc[r].x = fmaf(xv, wv.x, acc[r].x);
                acc[r].y = fmaf(xv, wv.y, acc[r].y);
                acc[r].z = fmaf(xv, wv.z, acc[r].z);
                acc[r].w = fmaf(xv, wv.w, acc[r].w);
            }
        }
        #pragma unroll
        for (int r = 0; r < 8; ++r) {
            ps[r][jq * 4 + 0][s] = acc[r].x;
            ps[r][jq * 4 + 1][s] = acc[r].y;
            ps[r][jq * 4 + 2][s] = acc[r].z;
            ps[r][jq * 4 + 3][s] = acc[r].w;
        }
    }
    __syncthreads();
    {
        const int bj0 = 64 * j;
        for (int e = t; e < 8 * 64; e += 256) {
            const int r = e >> 6, c = e & 63;
            float v = b1[bj0 + c];
            #pragma unroll
            for (int qq = 0; qq < 16; ++qq) v += ps[r][c][qq];
            h1[(size_t)(row0 + r) * H + bj0 + c] = fmaxf(v, 0.0f);
        }
    }
    __syncthreads();   // all h1 stores drained (per-wave vmcnt before barrier)
    if (t == 0) __hip_atomic_fetch_add(&done1[grp], 1, __ATOMIC_RELEASE, __HIP_MEMORY_SCOPE_AGENT);
    spin4(&done1[grp]);
    __syncthreads();

    // ---- phase 2: h2 tile = relu(h1 @ w2 + b2), cols 64j..64j+63 ----
    ((float4*)xs)[t]       = ((const float4*)(h1 + (size_t)row0 * H))[t];
    ((float4*)xs)[t + 256] = ((const float4*)(h1 + (size_t)row0 * H))[t + 256];
    __syncthreads();
    {
        const int bj0 = 64 * j;
        const float4* w4 = (const float4*)w2;
        const int wq = (bj0 >> 2) + jq;
        const int kbase = s * 16;
        float4 acc[8];
        #pragma unroll
        for (int r = 0; r < 8; ++r) acc[r] = (float4){0.f, 0.f, 0.f, 0.f};
        #pragma unroll
        for (int i = 0; i < 16; ++i) {
            const int k = kbase + i;
            const float4 wv = w4[k * (H / 4) + wq];
            #pragma unroll
            for (int r = 0; r < 8; ++r) {
                const float xv = xs[r][k];
                acc[r].x = fmaf(xv, wv.x, acc[r].x);
                acc[r].y = fmaf(xv, wv.y, acc[r].y);
                acc[r].z = fmaf(xv, wv.z, acc[r].z);
                acc[r].w = fmaf(xv, wv.w, acc[r].w);
            }
        }
        #pragma unroll
        for (int r = 0; r < 8; ++r) {
            ps[r][jq * 4 + 0][s] = acc[r].x;
            ps[r][jq * 4 + 1][s] = acc[r].y;
            ps[r][jq * 4 + 2][s] = acc[r].z;
            ps[r][jq * 4 + 3][s] = acc[r].w;
        }
    }
    __syncthreads();
    {
        const int bj0 = 64 * j;
        for (int e = t; e < 8 * 64; e += 256) {
            const int r = e >> 6, c = e & 63;
            float v = b2[bj0 + c];
            #pragma unroll
            for (int qq = 0; qq < 16; ++qq) v += ps[r][c][qq];
            h2[(size_t)(row0 + r) * H + bj0 + c] = fmaxf(v, 0.0f);
        }
    }
    __syncthreads();
    if (t == 0) __hip_atomic_fetch_add(&done2[grp], 1, __ATOMIC_RELEASE, __HIP_MEMORY_SCOPE_AGENT);
    if (j >= 2) return;                 // whole block exits uniformly
    spin4(&done2[grp]);
    __syncthreads();

    // ---- phase 3: logits, 48 cols at 48j (j in {0,1}) ----
    ((float4*)xs)[t]       = ((const float4*)(h2 + (size_t)row0 * H))[t];
    ((float4*)xs)[t + 256] = ((const float4*)(h2 + (size_t)row0 * H))[t + 256];
    __syncthreads();
    {
        const int bj0 = 48 * j;
        if (jq < 12) {
            const float4* w4 = (const float4*)wl;
            const int wq = (bj0 >> 2) + jq;
            const int kbase = s * 16;
            float4 acc[8];
            #pragma unroll
            for (int r = 0; r < 8; ++r) acc[r] = (float4){0.f, 0.f, 0.f, 0.f};
            #pragma unroll
            for (int i = 0; i < 16; ++i) {
                const int k = kbase + i;
                const float4 wv = w4[k * (C / 4) + wq];
                #pragma unroll
                for (int r = 0; r < 8; ++r) {
                    const float xv = xs[r][k];
                    acc[r].x = fmaf(xv, wv.x, acc[r].x);
                    acc[r].y = fmaf(xv, wv.y, acc[r].y);
                    acc[r].z = fmaf(xv, wv.z, acc[r].z);
                    acc[r].w = fmaf(xv, wv.w, acc[r].w);
                }
            }
            #pragma unroll
            for (int r = 0; r < 8; ++r) {
                ps[r][jq * 4 + 0][s] = acc[r].x;
                ps[r][jq * 4 + 1][s] = acc[r].y;
                ps[r][jq * 4 + 2][s] = acc[r].z;
                ps[r][jq * 4 + 3][s] = acc[r].w;
            }
        }
    }
    __syncthreads();
    {
        const int bj0 = 48 * j;
        for (int e = t; e < 8 * 48; e += 256) {
            const int r = e / 48, c = e % 48;
            float v = bl[bj0 + c];
            #pragma unroll
            for (int qq = 0; qq < 16; ++qq) v += ps[r][c][qq];
            out[(size_t)(row0 + r) * C + bj0 + c] = v;
        }
        if (j == 0 && t < 8) {
            const int row = row0 + t;
            out[(size_t)NSEG * C + row] = (float)(row % C);
            out[(size_t)NSEG * C + NSEG + row] = (float)(row / C);
        }
    }
}

extern "C" void kernel_launch(void* const* d_in, const int* in_sizes, int n_in,
                              void* d_out, int out_size, void* d_ws, size_t ws_size,
                              hipStream_t stream) {
    const float* feat  = (const float*)d_in[0];
    const int*   label = (const int*)d_in[1];
    const float* w1    = (const float*)d_in[2];
    const float* b1    = (const float*)d_in[3];
    const float* w2    = (const float*)d_in[4];
    const float* b2    = (const float*)d_in[5];
    const float* wl    = (const float*)d_in[6];
    const float* bl    = (const float*)d_in[7];
    float* out = (float*)d_out;

    char* ws = (char*)d_ws;
    const size_t KBYTES = (size_t)SPLIT * NSEG * H * 4;       // 6 MB partial keys
    int*   kbuf  = (int*)ws;
    int*   cnts  = (int*)(ws + KBYTES);                       // 24 KB
    int*   flags = (int*)(ws + KBYTES + 32768);               // done1[192]+done2[192]
    float* h1    = (float*)(ws + KBYTES + 65536);             // 1.5 MB
    float* h2    = (float*)(ws + KBYTES + 65536 + (size_t)NSEG * H * 4);

    pool_kernel<<<B * NFBLK * SPLIT, 256, 0, stream>>>(feat, label, kbuf, cnts, flags);
    fused_mlp<<<NGRP * 4, 256, 0, stream>>>(kbuf, cnts, w1, b1, w2, b2, wl, bl,
                                            h1, h2, out, flags, flags + NGRP);
}

// Round 15
// 44.444 us; speedup vs baseline: 3.9694x; 3.9694x over previous
//
#include <hip/hip_runtime.h>

#define B 16
#define F_DIM 256
#define P 8192
#define C 96
#define H 256
#define NSEG (B * C)          // 1536
#define G 8                   // feature rows per pool block
#define NFBLK (F_DIM / G)     // 32

// order-preserving float <-> uint mapping for atomicMax-based float max
__device__ __forceinline__ unsigned f2key(float x) {
    unsigned u = __float_as_uint(x);
    return (u & 0x80000000u) ? ~u : (u | 0x80000000u);
}
__device__ __forceinline__ float key2f(unsigned k) {
    unsigned u = (k & 0x80000000u) ? (k & 0x7FFFFFFFu) : ~k;
    return __uint_as_float(u);
}

// block = (batch b, feature group f0..f0+7): labels read ONCE (32 KB), reused
// across 8 feature rows (8 x 32 KB). Histogram computed locally (count fused).
__global__ __launch_bounds__(256) void pool_kernel(const float* __restrict__ feat,
                                                   const int* __restrict__ label,
                                                   float* __restrict__ pooled) {
    __shared__ unsigned smax[G][C];
    __shared__ int hist[C];
    const int blk = blockIdx.x;
    const int b = blk >> 5;            // / NFBLK
    const int f0 = (blk & 31) << 3;    // (blk % NFBLK) * G
    const int t = threadIdx.x;

    for (int i = t; i < G * C; i += 256) ((unsigned*)smax)[i] = 0u;  // key identity
    if (t < C) hist[t] = 0;
    __syncthreads();

    // this thread's 32 labels (8 int4), loaded once
    const int4* lrow4 = (const int4*)(label + (size_t)b * P);
    int4 lab[8];
    #pragma unroll
    for (int j = 0; j < 8; ++j) lab[j] = lrow4[t + j * 256];

    // local histogram (every block of batch b computes the same one)
    #pragma unroll
    for (int j = 0; j < 8; ++j) {
        atomicAdd(&hist[lab[j].x], 1);
        atomicAdd(&hist[lab[j].y], 1);
        atomicAdd(&hist[lab[j].z], 1);
        atomicAdd(&hist[lab[j].w], 1);
    }

    const float4* fbase4 = (const float4*)(feat + ((size_t)b * F_DIM + f0) * P);

    // 8 feature-row phases, 1-deep prefetch: load row f+1 while max-ing row f
    float4 cur[8], nxt[8];
    #pragma unroll
    for (int j = 0; j < 8; ++j) cur[j] = fbase4[t + j * 256];

    #pragma unroll 1
    for (int f = 0; f < G; ++f) {
        if (f + 1 < G) {
            #pragma unroll
            for (int j = 0; j < 8; ++j)
                nxt[j] = fbase4[(size_t)(f + 1) * (P / 4) + t + j * 256];
        }
        #pragma unroll
        for (int j = 0; j < 8; ++j) {
            atomicMax(&smax[f][lab[j].x], f2key(cur[j].x));
            atomicMax(&smax[f][lab[j].y], f2key(cur[j].y));
            atomicMax(&smax[f][lab[j].z], f2key(cur[j].z));
            atomicMax(&smax[f][lab[j].w], f2key(cur[j].w));
        }
        #pragma unroll
        for (int j = 0; j < 8; ++j) cur[j] = nxt[j];
    }
    __syncthreads();

    // epilogue: thread t < 96 owns class t, writes 8 features as 2 float4
    if (t < C) {
        const int cnt = hist[t];
        float4 lo, hi;
        float* lv = (float*)&lo;
        float* hv = (float*)&hi;
        #pragma unroll
        for (int f = 0; f < 4; ++f) {
            const float v = key2f(smax[f][t]);
            lv[f] = (cnt == 0) ? 0.0f : ((cnt == P) ? v : fmaxf(v, 0.0f));
        }
        #pragma unroll
        for (int f = 4; f < 8; ++f) {
            const float v = key2f(smax[f][t]);
            hv[f - 4] = (cnt == 0) ? 0.0f : ((cnt == P) ? v : fmaxf(v, 0.0f));
        }
        float* dst = &pooled[(size_t)(b * C + t) * F_DIM + f0];
        *(float4*)dst = lo;
        *(float4*)(dst + 4) = hi;
    }
}

// dense layer: y[NSEG x OUTW] = (relu?)(x[NSEG x H] @ w[H x OUTW] + bias)
// block: 8 rows x COLS cols; 256 threads = 16 col-quads x 16 k-slices (split-K).
template <int COLS, int RELU, int OUTW>
__global__ __launch_bounds__(256, 3) void dense_kernel(const float* __restrict__ x,
                                                       const float* __restrict__ w,
                                                       const float* __restrict__ bias,
                                                       float* __restrict__ y,
                                                       float* __restrict__ tails) {
    constexpr int NQ = COLS / 4;       // active col-quads (<= 16)
    __shared__ float xs[8][H];
    __shared__ float ps[8][COLS][17];  // [row][col][slice], padded
    const int t = threadIdx.x;
    const int row0 = blockIdx.x * 8;
    const int bj0 = blockIdx.y * COLS;

    // stage 8 rows of x (8 x 256 floats = 512 float4), coalesced
    {
        int i0 = t, i1 = t + 256;
        ((float4*)xs)[i0] = ((const float4*)(x + (size_t)row0 * H))[i0];
        ((float4*)xs)[i1] = ((const float4*)(x + (size_t)row0 * H))[i1];
    }
    __syncthreads();

    const int s = t >> 4;     // k-slice 0..15
    const int jq = t & 15;    // col-quad

    if (jq < NQ) {
        const float4* w4 = (const float4*)w;
        constexpr int WS4 = OUTW / 4;   // float4 per weight row
        const int wq = (bj0 >> 2) + jq;
        const int kbase = s * 16;
        float4 acc[8];
        #pragma unroll
        for (int r = 0; r < 8; ++r) acc[r] = (float4){0.f, 0.f, 0.f, 0.f};

        #pragma unroll
        for (int i = 0; i < 16; ++i) {
            const int k = kbase + i;
            const float4 wv = w4[k * WS4 + wq];
            #pragma unroll
            for (int r = 0; r < 8; ++r) {
                const float xv = xs[r][k];
                acc[r].x = fmaf(xv, wv.x, acc[r].x);
                acc[r].y = fmaf(xv, wv.y, acc[r].y);
                acc[r].z = fmaf(xv, wv.z, acc[r].z);
                acc[r].w = fmaf(xv, wv.w, acc[r].w);
            }
        }
        #pragma unroll
        for (int r = 0; r < 8; ++r) {
            ps[r][jq * 4 + 0][s] = acc[r].x;
            ps[r][jq * 4 + 1][s] = acc[r].y;
            ps[r][jq * 4 + 2][s] = acc[r].z;
            ps[r][jq * 4 + 3][s] = acc[r].w;
        }
    }
    __syncthreads();

    // reduce 16 slices + bias (+relu), write out
    for (int e = t; e < 8 * COLS; e += 256) {
        const int r = e / COLS, j = e % COLS;
        float v = bias[bj0 + j];
        #pragma unroll
        for (int q = 0; q < 16; ++q) v += ps[r][j][q];
        if (RELU) v = fmaxf(v, 0.0f);
        y[(size_t)(row0 + r) * OUTW + bj0 + j] = v;
    }

    // part_label / part_batch tails (only last layer passes tails != null)
    if (tails != nullptr && t < 8) {
        const int row = row0 + t;
        tails[row] = (float)(row % C);
        tails[NSEG + row] = (float)(row / C);
    }
}

extern "C" void kernel_launch(void* const* d_in, const int* in_sizes, int n_in,
                              void* d_out, int out_size, void* d_ws, size_t ws_size,
                              hipStream_t stream) {
    const float* feat  = (const float*)d_in[0];
    const int*   label = (const int*)d_in[1];
    const float* w1    = (const float*)d_in[2];
    const float* b1    = (const float*)d_in[3];
    const float* w2    = (const float*)d_in[4];
    const float* b2    = (const float*)d_in[5];
    const float* wl    = (const float*)d_in[6];
    const float* bl    = (const float*)d_in[7];
    float* out = (float*)d_out;

    char* ws = (char*)d_ws;
    float* pooled = (float*)ws;                            // 1.5 MB
    float* h1     = (float*)(ws + NSEG * H * 4);           // 1.5 MB
    float* h2     = (float*)(ws + 2 * NSEG * H * 4);       // 1.5 MB

    pool_kernel<<<B * NFBLK, 256, 0, stream>>>(feat, label, pooled);
    dense_kernel<64, 1, H><<<dim3(NSEG / 8, 4), 256, 0, stream>>>(pooled, w1, b1, h1, nullptr);
    dense_kernel<64, 1, H><<<dim3(NSEG / 8, 4), 256, 0, stream>>>(h1, w2, b2, h2, nullptr);
    dense_kernel<48, 0, C><<<dim3(NSEG / 8, 2), 256, 0, stream>>>(h2, wl, bl, out, out + (size_t)NSEG * C);
}